// Round 1
// baseline (6087.986 us; speedup 1.0000x reference)
//
#include <hip/hip_runtime.h>
#include <hip/hip_fp16.h>
#include <hip/hip_cooperative_groups.h>

namespace cg = cooperative_groups;

#define B_N 65536
#define K_N 256
#define D_N 128
#define N_ITER 50
#define NSHARD 16
#define BUFSTRIDE (NSHARD * K_N)  // floats per colsum buffer (16 shards x 256 cols)

constexpr float MU_EPS = 1.0f / 65536.0f + 1e-8f;  // exp(log_mu)
constexpr float NU_EPS = 1.0f / 256.0f + 1e-8f;    // exp(log_nu)
constexpr float KSCALE = 8192.0f;                  // keeps fp16 kappa in normal range
constexpr float INV_KSCALE = 1.0f / 8192.0f;
constexpr float NUKS = NU_EPS * KSCALE;
constexpr float MUKS = MU_EPS * KSCALE;

__device__ __forceinline__ float wave_sum(float v) {
#pragma unroll
    for (int m = 1; m < 64; m <<= 1) v += __shfl_xor(v, m, 64);
    return v;
}
__device__ __forceinline__ float wave_max(float v) {
#pragma unroll
    for (int m = 1; m < 64; m <<= 1) v = fmaxf(v, __shfl_xor(v, m, 64));
    return v;
}

// ---------------------------------------------------------------------------
// Blocks 0..255: L2-normalize prototype rows. Block 256: init colsum buffers
// (3-buffer rotation; buf2/shard0 = NUKS so that iteration 0 sees exp(v)=1)
// and zero d_out (harness poisons it with 0xAA before every launch).
// ---------------------------------------------------------------------------
__global__ __launch_bounds__(64) void proto_norm_init(
        const float* __restrict__ proto, float* __restrict__ yn,
        float* __restrict__ csbuf, float* __restrict__ out) {
    const int blk = blockIdx.x;
    const int lane = threadIdx.x;
    if (blk < 256) {
        float2 p = *(const float2*)&proto[blk * 128 + lane * 2];
        float ss = wave_sum(p.x * p.x + p.y * p.y);
        float inv = 1.0f / fmaxf(sqrtf(ss), 1e-12f);
        *(float2*)&yn[blk * 128 + lane * 2] = make_float2(p.x * inv, p.y * inv);
    } else {
        for (int i = lane; i < 3 * BUFSTRIDE; i += 64)
            csbuf[i] = (i >= 2 * BUFSTRIDE && i < 2 * BUFSTRIDE + K_N) ? NUKS : 0.0f;
        if (lane == 0) out[0] = 0.0f;
    }
}

// rn[i] = 1 / max(||x_i||, 1e-12)  (one wave per row, 16 rows per wave)
__global__ __launch_bounds__(256) void row_norm(const float* __restrict__ x,
                                                float* __restrict__ rn) {
    const int tid = threadIdx.x;
    const int wave = tid >> 6, lane = tid & 63;
    const int row0 = blockIdx.x * 64 + wave * 16;
    for (int r = 0; r < 16; r++) {
        const int row = row0 + r;
        float2 p = *(const float2*)&x[(size_t)row * 128 + lane * 2];
        float ss = wave_sum(p.x * p.x + p.y * p.y);
        if (lane == 0) rn[row] = 1.0f / fmaxf(sqrtf(ss), 1e-12f);
    }
}

// ---------------------------------------------------------------------------
// C[i,k] = 1 - (x_i . yn_k) * rn_i  ;  kappa = KSCALE*(exp(-C/eps)+1e-8) fp16
// 64x64 output tile / block, 4x4 register blocking per thread, fp32 vector ALU
// (no fp32 MFMA on CDNA4; 4.3 GFLOP total so vector is fine).
// ---------------------------------------------------------------------------
__global__ __launch_bounds__(256) void gemm_kc(
        const float* __restrict__ x, const float* __restrict__ yn,
        const float* __restrict__ rn,
        __half* __restrict__ kappa, __half* __restrict__ Cm) {
    __shared__ __align__(16) float as[16][68];  // transposed tiles: [kk][row]
    __shared__ __align__(16) float bs[16][68];  // 68-pad keeps 16B align + breaks conflicts
    const int tid = threadIdx.x;
    const int tx = tid & 15, ty = tid >> 4;
    const int row0 = blockIdx.x * 64, col0 = blockIdx.y * 64;
    const int lr = tid >> 2, lq = tid & 3;
    float acc[4][4] = {};
    const float rnv = rn[row0 + lr];
    for (int d0 = 0; d0 < 128; d0 += 16) {
        float4 av = *(const float4*)&x[(size_t)(row0 + lr) * 128 + d0 + lq * 4];
        float4 bv = *(const float4*)&yn[(col0 + lr) * 128 + d0 + lq * 4];
        as[lq * 4 + 0][lr] = av.x * rnv;
        as[lq * 4 + 1][lr] = av.y * rnv;
        as[lq * 4 + 2][lr] = av.z * rnv;
        as[lq * 4 + 3][lr] = av.w * rnv;
        bs[lq * 4 + 0][lr] = bv.x;
        bs[lq * 4 + 1][lr] = bv.y;
        bs[lq * 4 + 2][lr] = bv.z;
        bs[lq * 4 + 3][lr] = bv.w;
        __syncthreads();
#pragma unroll
        for (int kk = 0; kk < 16; kk++) {
            float4 a4 = *(const float4*)&as[kk][ty * 4];
            float4 b4 = *(const float4*)&bs[kk][tx * 4];
            float aa[4] = {a4.x, a4.y, a4.z, a4.w};
            float bb[4] = {b4.x, b4.y, b4.z, b4.w};
#pragma unroll
            for (int i = 0; i < 4; i++)
#pragma unroll
                for (int j = 0; j < 4; j++) acc[i][j] = fmaf(aa[i], bb[j], acc[i][j]);
        }
        __syncthreads();
    }
    union H4 { __half h[4]; uint2 u; };
#pragma unroll
    for (int i = 0; i < 4; i++) {
        const int row = row0 + ty * 4 + i;
        H4 hk, hc;
#pragma unroll
        for (int j = 0; j < 4; j++) {
            float Cv = 1.0f - acc[i][j];
            float kap = KSCALE * (__expf(-10.0f * Cv) + 1e-8f);
            hk.h[j] = __float2half(kap);
            hc.h[j] = __float2half(Cv);
        }
        size_t off = (size_t)row * 256 + col0 + tx * 4;
        *(uint2*)&kappa[off] = hk.u;
        *(uint2*)&Cm[off] = hc.u;
    }
}

// ---------------------------------------------------------------------------
// 50 Sinkhorn iterations, multiplicative domain, one cooperative kernel.
// Per iteration: exp(v) from previous colsums; per row: rowsum -> a=exp(u);
// accumulate new colsums with fresh a. One grid.sync per iteration.
// 3-buffer colsum rotation: read (t+2)%3, accumulate t%3, zero (t+1)%3.
// Block g always owns rows [g*64, g*64+64) -> its kappa slice stays in its
// XCD's L2 across all 50 iterations (blocks are resident).
// ---------------------------------------------------------------------------
__global__ __launch_bounds__(256, 4) void sinkhorn_iter(
        const __half* __restrict__ kappa, float* __restrict__ csbuf,
        float* __restrict__ aexp) {
    cg::grid_group grid = cg::this_grid();
    __shared__ __align__(16) float ev_lds[256];
    __shared__ __align__(16) float cs_lds[4][256];
    const int blk = blockIdx.x, tid = threadIdx.x;
    const int wave = tid >> 6, lane = tid & 63;
    const int row0 = blk * 64 + wave * 16;
    const uint2* kbase = (const uint2*)kappa;  // 4 halves per uint2
    for (int t = 0; t < N_ITER; t++) {
        const int p_read = (t + 2) % 3, p_acc = t % 3, p_zero = (t + 1) % 3;
        {   // exp(v_k) = NU_EPS*KSCALE / colsum_k   (thread tid owns column tid)
            const float* cb = csbuf + p_read * BUFSTRIDE;
            float cs = 0.0f;
#pragma unroll
            for (int s = 0; s < NSHARD; s++) cs += cb[s * 256 + tid];
            ev_lds[tid] = NUKS / cs;
        }
        if (blk < NSHARD) csbuf[p_zero * BUFSTRIDE + blk * 256 + tid] = 0.0f;
        __syncthreads();
        float4 ev = *(const float4*)&ev_lds[lane * 4];  // cols 4*lane..4*lane+3
        float c0 = 0, c1 = 0, c2 = 0, c3 = 0;
#pragma unroll 4
        for (int r = 0; r < 16; r++) {
            const int row = row0 + r;
            union { uint2 u; __half2 h[2]; } ku;
            ku.u = kbase[(size_t)row * 64 + lane];  // whole row in one wave load
            float2 f01 = __half22float2(ku.h[0]);
            float2 f23 = __half22float2(ku.h[1]);
            float part = f01.x * ev.x + f01.y * ev.y + f23.x * ev.z + f23.y * ev.w;
            float S = wave_sum(part);     // scaled rowsum of kappa*exp(v)
            float ai = MUKS / S;          // = exp(u_i)
            if (t == N_ITER - 1 && lane == 0) aexp[row] = ai;
            c0 = fmaf(f01.x, ai, c0);
            c1 = fmaf(f01.y, ai, c1);
            c2 = fmaf(f23.x, ai, c2);
            c3 = fmaf(f23.y, ai, c3);
        }
        *(float4*)&cs_lds[wave][lane * 4] = make_float4(c0, c1, c2, c3);
        __syncthreads();
        float v = cs_lds[0][tid] + cs_lds[1][tid] + cs_lds[2][tid] + cs_lds[3][tid];
        atomicAdd(&csbuf[p_acc * BUFSTRIDE + (blk & (NSHARD - 1)) * 256 + tid], v);
        grid.sync();
    }
}

// ---------------------------------------------------------------------------
// out = sum_{i,k} pi * C * softmax(|coord|)  with pi = a_i * ev_k * kappa/KSCALE
// ---------------------------------------------------------------------------
__global__ __launch_bounds__(256) void finalize(
        const __half* __restrict__ kappa, const __half* __restrict__ Cm,
        const float* __restrict__ coord, const float* __restrict__ aexp,
        const float* __restrict__ csfin, float* __restrict__ out) {
    __shared__ __align__(16) float ev_lds[256];
    __shared__ float wpart[4];
    const int tid = threadIdx.x, wave = tid >> 6, lane = tid & 63;
    {
        float cs = 0.0f;
#pragma unroll
        for (int s = 0; s < NSHARD; s++) cs += csfin[s * 256 + tid];
        ev_lds[tid] = NUKS / cs;
    }
    __syncthreads();
    float4 ev = *(const float4*)&ev_lds[lane * 4];
    const int row0 = blockIdx.x * 64 + wave * 16;
    float acc = 0.0f;
    for (int r = 0; r < 16; r++) {
        const int row = row0 + r;
        float ai = aexp[row];
        float4 co = *(const float4*)&coord[(size_t)row * 256 + lane * 4];
        float a0 = fabsf(co.x), a1 = fabsf(co.y), a2 = fabsf(co.z), a3 = fabsf(co.w);
        float mx = wave_max(fmaxf(fmaxf(a0, a1), fmaxf(a2, a3)));
        float e0 = __expf(a0 - mx), e1 = __expf(a1 - mx);
        float e2 = __expf(a2 - mx), e3 = __expf(a3 - mx);
        float Z = wave_sum(e0 + e1 + e2 + e3);
        union { uint2 u; __half2 h[2]; } ku, cu;
        ku.u = *(const uint2*)&kappa[(size_t)row * 256 + lane * 4];
        cu.u = *(const uint2*)&Cm[(size_t)row * 256 + lane * 4];
        float2 k01 = __half22float2(ku.h[0]), k23 = __half22float2(ku.h[1]);
        float2 c01 = __half22float2(cu.h[0]), c23 = __half22float2(cu.h[1]);
        float s = k01.x * ev.x * c01.x * e0 + k01.y * ev.y * c01.y * e1 +
                  k23.x * ev.z * c23.x * e2 + k23.y * ev.w * c23.y * e3;
        acc = fmaf(s, ai * INV_KSCALE / Z, acc);
    }
    acc = wave_sum(acc);
    if (lane == 0) wpart[wave] = acc;
    __syncthreads();
    if (tid == 0) atomicAdd(out, wpart[0] + wpart[1] + wpart[2] + wpart[3]);
}

extern "C" void kernel_launch(void* const* d_in, const int* in_sizes, int n_in,
                              void* d_out, int out_size, void* d_ws, size_t ws_size,
                              hipStream_t stream) {
    const float* x = (const float*)d_in[0];
    const float* proto = (const float*)d_in[1];
    const float* coord = (const float*)d_in[2];
    float* out = (float*)d_out;
    char* ws = (char*)d_ws;
    // workspace layout (~64.7 MB total)
    __half* kappa = (__half*)(ws);                                  // 32 MB
    __half* Cm = (__half*)(ws + (size_t)B_N * K_N * 2);             // 32 MB
    float* yn = (float*)(ws + (size_t)B_N * K_N * 4);               // 128 KB
    float* rn = (float*)(ws + (size_t)B_N * K_N * 4 + 131072);      // 256 KB
    float* aexp = (float*)(ws + (size_t)B_N * K_N * 4 + 131072 + 262144);  // 256 KB
    float* csbuf = (float*)(ws + (size_t)B_N * K_N * 4 + 131072 + 2 * 262144);  // 48 KB

    hipLaunchKernelGGL(proto_norm_init, dim3(257), dim3(64), 0, stream, proto, yn, csbuf, out);
    hipLaunchKernelGGL(row_norm, dim3(1024), dim3(256), 0, stream, x, rn);
    hipLaunchKernelGGL(gemm_kc, dim3(1024, 4), dim3(256), 0, stream, x, yn, rn, kappa, Cm);
    {
        void* args[3];
        args[0] = (void*)&kappa;
        args[1] = (void*)&csbuf;
        args[2] = (void*)&aexp;
        hipLaunchCooperativeKernel((void*)sinkhorn_iter, dim3(1024), dim3(256), args, 0, stream);
    }
    const float* csfin = csbuf + ((N_ITER - 1) % 3) * BUFSTRIDE;  // parity of t=49
    hipLaunchKernelGGL(finalize, dim3(1024), dim3(256), 0, stream, kappa, Cm, coord, aexp, csfin, out);
}

// Round 2
// 799.922 us; speedup vs baseline: 7.6107x; 7.6107x over previous
//
#include <hip/hip_runtime.h>
#include <hip/hip_fp16.h>

#define B_N 65536
#define K_N 256
#define D_N 128
#define N_ITER 50
#define NSHARD 16
#define BUFSTRIDE (NSHARD * K_N)  // floats per colsum buffer (16 shards x 256 cols)

constexpr float MU_EPS = 1.0f / 65536.0f + 1e-8f;  // exp(log_mu)
constexpr float NU_EPS = 1.0f / 256.0f + 1e-8f;    // exp(log_nu)
constexpr float KSCALE = 8192.0f;                  // keeps fp16 kappa in normal range
constexpr float INV_KSCALE = 1.0f / 8192.0f;
constexpr float NUKS = NU_EPS * KSCALE;
constexpr float MUKS = MU_EPS * KSCALE;

__device__ __forceinline__ float wave_sum(float v) {
#pragma unroll
    for (int m = 1; m < 64; m <<= 1) v += __shfl_xor(v, m, 64);
    return v;
}
__device__ __forceinline__ float wave_max(float v) {
#pragma unroll
    for (int m = 1; m < 64; m <<= 1) v = fmaxf(v, __shfl_xor(v, m, 64));
    return v;
}

// ---------------------------------------------------------------------------
// Blocks 0..255: L2-normalize prototype rows. Block 256: init colsum buffers
// (3-buffer rotation; buf2/shard0 = NUKS so that iteration 0 sees exp(v)=1)
// and zero d_out (harness poisons it with 0xAA before every launch).
// ---------------------------------------------------------------------------
__global__ __launch_bounds__(64) void proto_norm_init(
        const float* __restrict__ proto, float* __restrict__ yn,
        float* __restrict__ csbuf, float* __restrict__ out) {
    const int blk = blockIdx.x;
    const int lane = threadIdx.x;
    if (blk < 256) {
        float2 p = *(const float2*)&proto[blk * 128 + lane * 2];
        float ss = wave_sum(p.x * p.x + p.y * p.y);
        float inv = 1.0f / fmaxf(sqrtf(ss), 1e-12f);
        *(float2*)&yn[blk * 128 + lane * 2] = make_float2(p.x * inv, p.y * inv);
    } else {
        for (int i = lane; i < 3 * BUFSTRIDE; i += 64)
            csbuf[i] = (i >= 2 * BUFSTRIDE && i < 2 * BUFSTRIDE + K_N) ? NUKS : 0.0f;
        if (lane == 0) out[0] = 0.0f;
    }
}

// rn[i] = 1 / max(||x_i||, 1e-12)  (one wave per row, 16 rows per wave)
__global__ __launch_bounds__(256) void row_norm(const float* __restrict__ x,
                                                float* __restrict__ rn) {
    const int tid = threadIdx.x;
    const int wave = tid >> 6, lane = tid & 63;
    const int row0 = blockIdx.x * 64 + wave * 16;
    for (int r = 0; r < 16; r++) {
        const int row = row0 + r;
        float2 p = *(const float2*)&x[(size_t)row * 128 + lane * 2];
        float ss = wave_sum(p.x * p.x + p.y * p.y);
        if (lane == 0) rn[row] = 1.0f / fmaxf(sqrtf(ss), 1e-12f);
    }
}

// ---------------------------------------------------------------------------
// C[i,k] = 1 - (x_i . yn_k) * rn_i  ;  kappa = KSCALE*(exp(-C/eps)+1e-8) fp16
// 64x64 output tile / block, 4x4 register blocking per thread, fp32 vector ALU
// (no fp32 MFMA on CDNA4; 4.3 GFLOP total so vector is fine).
// ---------------------------------------------------------------------------
__global__ __launch_bounds__(256) void gemm_kc(
        const float* __restrict__ x, const float* __restrict__ yn,
        const float* __restrict__ rn,
        __half* __restrict__ kappa, __half* __restrict__ Cm) {
    __shared__ __align__(16) float as[16][68];  // transposed tiles: [kk][row]
    __shared__ __align__(16) float bs[16][68];  // 68-pad keeps 16B align + breaks conflicts
    const int tid = threadIdx.x;
    const int tx = tid & 15, ty = tid >> 4;
    const int row0 = blockIdx.x * 64, col0 = blockIdx.y * 64;
    const int lr = tid >> 2, lq = tid & 3;
    float acc[4][4] = {};
    const float rnv = rn[row0 + lr];
    for (int d0 = 0; d0 < 128; d0 += 16) {
        float4 av = *(const float4*)&x[(size_t)(row0 + lr) * 128 + d0 + lq * 4];
        float4 bv = *(const float4*)&yn[(col0 + lr) * 128 + d0 + lq * 4];
        as[lq * 4 + 0][lr] = av.x * rnv;
        as[lq * 4 + 1][lr] = av.y * rnv;
        as[lq * 4 + 2][lr] = av.z * rnv;
        as[lq * 4 + 3][lr] = av.w * rnv;
        bs[lq * 4 + 0][lr] = bv.x;
        bs[lq * 4 + 1][lr] = bv.y;
        bs[lq * 4 + 2][lr] = bv.z;
        bs[lq * 4 + 3][lr] = bv.w;
        __syncthreads();
#pragma unroll
        for (int kk = 0; kk < 16; kk++) {
            float4 a4 = *(const float4*)&as[kk][ty * 4];
            float4 b4 = *(const float4*)&bs[kk][tx * 4];
            float aa[4] = {a4.x, a4.y, a4.z, a4.w};
            float bb[4] = {b4.x, b4.y, b4.z, b4.w};
#pragma unroll
            for (int i = 0; i < 4; i++)
#pragma unroll
                for (int j = 0; j < 4; j++) acc[i][j] = fmaf(aa[i], bb[j], acc[i][j]);
        }
        __syncthreads();
    }
    union H4 { __half h[4]; uint2 u; };
#pragma unroll
    for (int i = 0; i < 4; i++) {
        const int row = row0 + ty * 4 + i;
        H4 hk, hc;
#pragma unroll
        for (int j = 0; j < 4; j++) {
            float Cv = 1.0f - acc[i][j];
            float kap = KSCALE * (__expf(-10.0f * Cv) + 1e-8f);
            hk.h[j] = __float2half(kap);
            hc.h[j] = __float2half(Cv);
        }
        size_t off = (size_t)row * 256 + col0 + tx * 4;
        *(uint2*)&kappa[off] = hk.u;
        *(uint2*)&Cm[off] = hc.u;
    }
}

// ---------------------------------------------------------------------------
// ONE Sinkhorn iteration per launch (t = iteration index, passed as arg).
// Kernel boundaries on the stream provide the device-wide barrier + cache
// coherence that cg::grid.sync() was providing at ~120us each; graph-replay
// launch overhead is ~2-4us per node instead.
// Per iteration: exp(v) from previous colsums; per row: rowsum -> a=exp(u);
// accumulate new colsums with fresh a.
// 3-buffer colsum rotation: read (t+2)%3, accumulate t%3, zero (t+1)%3
// (zeroed buffer is only touched again in a LATER launch -> race-free).
// ---------------------------------------------------------------------------
__global__ __launch_bounds__(256) void sinkhorn_step(
        const __half* __restrict__ kappa, float* __restrict__ csbuf,
        float* __restrict__ aexp, int t) {
    __shared__ __align__(16) float ev_lds[256];
    __shared__ __align__(16) float cs_lds[4][256];
    const int blk = blockIdx.x, tid = threadIdx.x;
    const int wave = tid >> 6, lane = tid & 63;
    const int row0 = blk * 64 + wave * 16;
    const uint2* kbase = (const uint2*)kappa;  // 4 halves per uint2
    const int p_read = (t + 2) % 3, p_acc = t % 3, p_zero = (t + 1) % 3;
    {   // exp(v_k) = NU_EPS*KSCALE / colsum_k   (thread tid owns column tid)
        const float* cb = csbuf + p_read * BUFSTRIDE;
        float cs = 0.0f;
#pragma unroll
        for (int s = 0; s < NSHARD; s++) cs += cb[s * 256 + tid];
        ev_lds[tid] = NUKS / cs;
    }
    if (blk < NSHARD) csbuf[p_zero * BUFSTRIDE + blk * 256 + tid] = 0.0f;
    __syncthreads();
    float4 ev = *(const float4*)&ev_lds[lane * 4];  // cols 4*lane..4*lane+3
    float c0 = 0, c1 = 0, c2 = 0, c3 = 0;
#pragma unroll 4
    for (int r = 0; r < 16; r++) {
        const int row = row0 + r;
        union { uint2 u; __half2 h[2]; } ku;
        ku.u = kbase[(size_t)row * 64 + lane];  // whole row in one wave load
        float2 f01 = __half22float2(ku.h[0]);
        float2 f23 = __half22float2(ku.h[1]);
        float part = f01.x * ev.x + f01.y * ev.y + f23.x * ev.z + f23.y * ev.w;
        float S = wave_sum(part);     // scaled rowsum of kappa*exp(v)
        float ai = MUKS / S;          // = exp(u_i)
        if (t == N_ITER - 1 && lane == 0) aexp[row] = ai;  // uniform branch
        c0 = fmaf(f01.x, ai, c0);
        c1 = fmaf(f01.y, ai, c1);
        c2 = fmaf(f23.x, ai, c2);
        c3 = fmaf(f23.y, ai, c3);
    }
    *(float4*)&cs_lds[wave][lane * 4] = make_float4(c0, c1, c2, c3);
    __syncthreads();
    float v = cs_lds[0][tid] + cs_lds[1][tid] + cs_lds[2][tid] + cs_lds[3][tid];
    atomicAdd(&csbuf[p_acc * BUFSTRIDE + (blk & (NSHARD - 1)) * 256 + tid], v);
}

// ---------------------------------------------------------------------------
// out = sum_{i,k} pi * C * softmax(|coord|)  with pi = a_i * ev_k * kappa/KSCALE
// ---------------------------------------------------------------------------
__global__ __launch_bounds__(256) void finalize(
        const __half* __restrict__ kappa, const __half* __restrict__ Cm,
        const float* __restrict__ coord, const float* __restrict__ aexp,
        const float* __restrict__ csfin, float* __restrict__ out) {
    __shared__ __align__(16) float ev_lds[256];
    __shared__ float wpart[4];
    const int tid = threadIdx.x, wave = tid >> 6, lane = tid & 63;
    {
        float cs = 0.0f;
#pragma unroll
        for (int s = 0; s < NSHARD; s++) cs += csfin[s * 256 + tid];
        ev_lds[tid] = NUKS / cs;
    }
    __syncthreads();
    float4 ev = *(const float4*)&ev_lds[lane * 4];
    const int row0 = blockIdx.x * 64 + wave * 16;
    float acc = 0.0f;
    for (int r = 0; r < 16; r++) {
        const int row = row0 + r;
        float ai = aexp[row];
        float4 co = *(const float4*)&coord[(size_t)row * 256 + lane * 4];
        float a0 = fabsf(co.x), a1 = fabsf(co.y), a2 = fabsf(co.z), a3 = fabsf(co.w);
        float mx = wave_max(fmaxf(fmaxf(a0, a1), fmaxf(a2, a3)));
        float e0 = __expf(a0 - mx), e1 = __expf(a1 - mx);
        float e2 = __expf(a2 - mx), e3 = __expf(a3 - mx);
        float Z = wave_sum(e0 + e1 + e2 + e3);
        union { uint2 u; __half2 h[2]; } ku, cu;
        ku.u = *(const uint2*)&kappa[(size_t)row * 256 + lane * 4];
        cu.u = *(const uint2*)&Cm[(size_t)row * 256 + lane * 4];
        float2 k01 = __half22float2(ku.h[0]), k23 = __half22float2(ku.h[1]);
        float2 c01 = __half22float2(cu.h[0]), c23 = __half22float2(cu.h[1]);
        float s = k01.x * ev.x * c01.x * e0 + k01.y * ev.y * c01.y * e1 +
                  k23.x * ev.z * c23.x * e2 + k23.y * ev.w * c23.y * e3;
        acc = fmaf(s, ai * INV_KSCALE / Z, acc);
    }
    acc = wave_sum(acc);
    if (lane == 0) wpart[wave] = acc;
    __syncthreads();
    if (tid == 0) atomicAdd(out, wpart[0] + wpart[1] + wpart[2] + wpart[3]);
}

extern "C" void kernel_launch(void* const* d_in, const int* in_sizes, int n_in,
                              void* d_out, int out_size, void* d_ws, size_t ws_size,
                              hipStream_t stream) {
    const float* x = (const float*)d_in[0];
    const float* proto = (const float*)d_in[1];
    const float* coord = (const float*)d_in[2];
    float* out = (float*)d_out;
    char* ws = (char*)d_ws;
    // workspace layout (~64.7 MB total)
    __half* kappa = (__half*)(ws);                                  // 32 MB
    __half* Cm = (__half*)(ws + (size_t)B_N * K_N * 2);             // 32 MB
    float* yn = (float*)(ws + (size_t)B_N * K_N * 4);               // 128 KB
    float* rn = (float*)(ws + (size_t)B_N * K_N * 4 + 131072);      // 256 KB
    float* aexp = (float*)(ws + (size_t)B_N * K_N * 4 + 131072 + 262144);  // 256 KB
    float* csbuf = (float*)(ws + (size_t)B_N * K_N * 4 + 131072 + 2 * 262144);  // 48 KB

    hipLaunchKernelGGL(proto_norm_init, dim3(257), dim3(64), 0, stream, proto, yn, csbuf, out);
    hipLaunchKernelGGL(row_norm, dim3(1024), dim3(256), 0, stream, x, rn);
    hipLaunchKernelGGL(gemm_kc, dim3(1024, 4), dim3(256), 0, stream, x, yn, rn, kappa, Cm);
    for (int t = 0; t < N_ITER; t++) {
        hipLaunchKernelGGL(sinkhorn_step, dim3(1024), dim3(256), 0, stream,
                           kappa, csbuf, aexp, t);
    }
    const float* csfin = csbuf + ((N_ITER - 1) % 3) * BUFSTRIDE;  // parity of t=49
    hipLaunchKernelGGL(finalize, dim3(1024), dim3(256), 0, stream, kappa, Cm, coord, aexp, csfin, out);
}

// Round 3
// 544.019 us; speedup vs baseline: 11.1908x; 1.4704x over previous
//
#include <hip/hip_runtime.h>
#include <hip/hip_fp16.h>

#define B_N 65536
#define K_N 256
#define D_N 128
#define N_ITER 50
#define NSHARD 8
#define BUFSTRIDE (NSHARD * K_N)  // 2048 floats per colsum buffer (8 shards x 256)

constexpr float MU_EPS = 1.0f / 65536.0f + 1e-8f;  // exp(log_mu)
constexpr float NU_EPS = 1.0f / 256.0f + 1e-8f;    // exp(log_nu)
constexpr float KSCALE = 8192.0f;                  // keeps fp16 kappa in normal range
constexpr float INV_KSCALE = 1.0f / 8192.0f;
constexpr float NUKS = NU_EPS * KSCALE;
constexpr float MUKS = MU_EPS * KSCALE;

__device__ __forceinline__ float wave_sum(float v) {
#pragma unroll
    for (int m = 1; m < 64; m <<= 1) v += __shfl_xor(v, m, 64);
    return v;
}
__device__ __forceinline__ float wave_max(float v) {
#pragma unroll
    for (int m = 1; m < 64; m <<= 1) v = fmaxf(v, __shfl_xor(v, m, 64));
    return v;
}

// ---------------------------------------------------------------------------
// Blocks 0..255: L2-normalize prototype rows. Block 256: init colsum buffers
// (3-buffer rotation; buf2/shard0 = NUKS so iteration 0 sees exp(v)=1) and
// zero d_out (harness poisons it with 0xAA before every launch).
// ---------------------------------------------------------------------------
__global__ __launch_bounds__(64) void proto_norm_init(
        const float* __restrict__ proto, float* __restrict__ yn,
        float* __restrict__ csbuf, float* __restrict__ out) {
    const int blk = blockIdx.x;
    const int lane = threadIdx.x;
    if (blk < 256) {
        float2 p = *(const float2*)&proto[blk * 128 + lane * 2];
        float ss = wave_sum(p.x * p.x + p.y * p.y);
        float inv = 1.0f / fmaxf(sqrtf(ss), 1e-12f);
        *(float2*)&yn[blk * 128 + lane * 2] = make_float2(p.x * inv, p.y * inv);
    } else {
        for (int i = lane; i < 3 * BUFSTRIDE; i += 64)
            csbuf[i] = (i >= 2 * BUFSTRIDE && i < 2 * BUFSTRIDE + K_N) ? NUKS : 0.0f;
        if (lane == 0) out[0] = 0.0f;
    }
}

// rn[i] = 1 / max(||x_i||, 1e-12)  (one wave per row, 16 rows per wave)
__global__ __launch_bounds__(256) void row_norm(const float* __restrict__ x,
                                                float* __restrict__ rn) {
    const int tid = threadIdx.x;
    const int wave = tid >> 6, lane = tid & 63;
    const int row0 = blockIdx.x * 64 + wave * 16;
    for (int r = 0; r < 16; r++) {
        const int row = row0 + r;
        float2 p = *(const float2*)&x[(size_t)row * 128 + lane * 2];
        float ss = wave_sum(p.x * p.x + p.y * p.y);
        if (lane == 0) rn[row] = 1.0f / fmaxf(sqrtf(ss), 1e-12f);
    }
}

// ---------------------------------------------------------------------------
// C[i,k] = 1 - (x_i . yn_k) * rn_i  ;  kappa = KSCALE*(exp(-C/eps)+1e-8) fp16
// C is NOT stored: finalize recovers it as -eps*ln(kappa/KSCALE - 1e-8).
// ---------------------------------------------------------------------------
__global__ __launch_bounds__(256) void gemm_kc(
        const float* __restrict__ x, const float* __restrict__ yn,
        const float* __restrict__ rn, __half* __restrict__ kappa) {
    __shared__ __align__(16) float as[16][68];  // transposed tiles: [kk][row]
    __shared__ __align__(16) float bs[16][68];
    const int tid = threadIdx.x;
    const int tx = tid & 15, ty = tid >> 4;
    const int row0 = blockIdx.x * 64, col0 = blockIdx.y * 64;
    const int lr = tid >> 2, lq = tid & 3;
    float acc[4][4] = {};
    const float rnv = rn[row0 + lr];
    for (int d0 = 0; d0 < 128; d0 += 16) {
        float4 av = *(const float4*)&x[(size_t)(row0 + lr) * 128 + d0 + lq * 4];
        float4 bv = *(const float4*)&yn[(col0 + lr) * 128 + d0 + lq * 4];
        as[lq * 4 + 0][lr] = av.x * rnv;
        as[lq * 4 + 1][lr] = av.y * rnv;
        as[lq * 4 + 2][lr] = av.z * rnv;
        as[lq * 4 + 3][lr] = av.w * rnv;
        bs[lq * 4 + 0][lr] = bv.x;
        bs[lq * 4 + 1][lr] = bv.y;
        bs[lq * 4 + 2][lr] = bv.z;
        bs[lq * 4 + 3][lr] = bv.w;
        __syncthreads();
#pragma unroll
        for (int kk = 0; kk < 16; kk++) {
            float4 a4 = *(const float4*)&as[kk][ty * 4];
            float4 b4 = *(const float4*)&bs[kk][tx * 4];
            float aa[4] = {a4.x, a4.y, a4.z, a4.w};
            float bb[4] = {b4.x, b4.y, b4.z, b4.w};
#pragma unroll
            for (int i = 0; i < 4; i++)
#pragma unroll
                for (int j = 0; j < 4; j++) acc[i][j] = fmaf(aa[i], bb[j], acc[i][j]);
        }
        __syncthreads();
    }
    union H4 { __half h[4]; uint2 u; };
#pragma unroll
    for (int i = 0; i < 4; i++) {
        const int row = row0 + ty * 4 + i;
        H4 hk;
#pragma unroll
        for (int j = 0; j < 4; j++) {
            float Cv = 1.0f - acc[i][j];
            hk.h[j] = __float2half(KSCALE * (__expf(-10.0f * Cv) + 1e-8f));
        }
        *(uint2*)&kappa[(size_t)row * 256 + col0 + tx * 4] = hk.u;
    }
}

// ---------------------------------------------------------------------------
// ONE Sinkhorn iteration per launch. Lane layout: g = lane>>4 (row in group of
// 4), c = lane&15 (16-column chunk). Each wave processes 4 rows at a time;
// row reduction = 4 shuffle stages over 16 lanes (vs 6 over 64). All 8 kappa
// dwordx4 loads issued up front. rcp instead of fp32 div.
// 3-buffer colsum rotation: read (t+2)%3, accumulate t%3, zero (t+1)%3.
// ---------------------------------------------------------------------------
__global__ __launch_bounds__(256) void sinkhorn_step(
        const __half* __restrict__ kappa, float* __restrict__ csbuf,
        float* __restrict__ aexp, int t) {
    __shared__ __align__(16) float ev_lds[256];
    __shared__ float cs_lds[4 * 273];  // [wave][chunk*17 + j] — stride-17 kills conflicts
    const int blk = blockIdx.x, tid = threadIdx.x;
    const int w = tid >> 6, lane = tid & 63;
    const int g = lane >> 4, c = lane & 15;
    const int p_read = (t + 2) % 3, p_acc = t % 3, p_zero = (t + 1) % 3;
    {   // exp(v_k)*? : ev = NUKS / colsum_k (thread tid owns column tid)
        const float* cb = csbuf + p_read * BUFSTRIDE;
        float cs = 0.0f;
#pragma unroll
        for (int s = 0; s < NSHARD; s++) cs += cb[s * 256 + tid];
        ev_lds[tid] = NUKS * __builtin_amdgcn_rcpf(cs);
    }
    if (blk < NSHARD) csbuf[p_zero * BUFSTRIDE + blk * 256 + tid] = 0.0f;
    __syncthreads();
    float e[16];
    {
        float4 e0 = *(const float4*)&ev_lds[c * 16 + 0];
        float4 e1 = *(const float4*)&ev_lds[c * 16 + 4];
        float4 e2 = *(const float4*)&ev_lds[c * 16 + 8];
        float4 e3 = *(const float4*)&ev_lds[c * 16 + 12];
        e[0] = e0.x; e[1] = e0.y; e[2] = e0.z; e[3] = e0.w;
        e[4] = e1.x; e[5] = e1.y; e[6] = e1.z; e[7] = e1.w;
        e[8] = e2.x; e[9] = e2.y; e[10] = e2.z; e[11] = e2.w;
        e[12] = e3.x; e[13] = e3.y; e[14] = e3.z; e[15] = e3.w;
    }
    const int row_base = blk * 64 + w * 16 + g;  // + rg*4
    const uint4* kb = (const uint4*)kappa;       // 8 halves per uint4; row = 32 uint4
    uint4 kv[4][2];
#pragma unroll
    for (int rg = 0; rg < 4; rg++) {             // batch all loads for latency
        const size_t base = (size_t)(row_base + rg * 4) * 32 + c * 2;
        kv[rg][0] = kb[base];
        kv[rg][1] = kb[base + 1];
    }
    float acc[16];
#pragma unroll
    for (int j = 0; j < 16; j++) acc[j] = 0.0f;
#pragma unroll
    for (int rg = 0; rg < 4; rg++) {
        float kf[16];
        const __half2* h0 = (const __half2*)&kv[rg][0];
        const __half2* h1 = (const __half2*)&kv[rg][1];
#pragma unroll
        for (int q = 0; q < 4; q++) {
            float2 f = __half22float2(h0[q]);
            kf[2 * q] = f.x; kf[2 * q + 1] = f.y;
            float2 g2 = __half22float2(h1[q]);
            kf[8 + 2 * q] = g2.x; kf[8 + 2 * q + 1] = g2.y;
        }
        float part = 0.0f;
#pragma unroll
        for (int j = 0; j < 16; j++) part = fmaf(kf[j], e[j], part);
        part += __shfl_xor(part, 8, 64);   // 16-lane tree: 4 rows reduce in parallel
        part += __shfl_xor(part, 4, 64);
        part += __shfl_xor(part, 2, 64);
        part += __shfl_xor(part, 1, 64);
        float ai = MUKS * __builtin_amdgcn_rcpf(part);  // = exp(u_row)
        if (t == N_ITER - 1 && c == 0) aexp[row_base + rg * 4] = ai;
#pragma unroll
        for (int j = 0; j < 16; j++) acc[j] = fmaf(kf[j], ai, acc[j]);
    }
    // combine the 4 row-groups (same columns) via cross-group shuffles
#pragma unroll
    for (int j = 0; j < 16; j++) {
        acc[j] += __shfl_xor(acc[j], 16, 64);
        acc[j] += __shfl_xor(acc[j], 32, 64);
    }
    if (g == 0) {
#pragma unroll
        for (int j = 0; j < 16; j++) cs_lds[w * 273 + c * 17 + j] = acc[j];
    }
    __syncthreads();
    float v = 0.0f;
#pragma unroll
    for (int p = 0; p < 4; p++) v += cs_lds[p * 273 + (tid >> 4) * 17 + (tid & 15)];
    atomicAdd(&csbuf[p_acc * BUFSTRIDE + (blk & (NSHARD - 1)) * 256 + tid], v);
}

// ---------------------------------------------------------------------------
// out = sum_{i,k} pi * C * softmax(|coord|),  pi = a_i * ev_k * kappa/KSCALE,
// C recovered as -eps*ln(kappa*INV_KSCALE - 1e-8) (exact inverse of gemm_kc).
// ---------------------------------------------------------------------------
__global__ __launch_bounds__(256) void finalize(
        const __half* __restrict__ kappa, const float* __restrict__ coord,
        const float* __restrict__ aexp, const float* __restrict__ csfin,
        float* __restrict__ out) {
    __shared__ __align__(16) float ev_lds[256];
    __shared__ float wpart[4];
    const int tid = threadIdx.x, wave = tid >> 6, lane = tid & 63;
    {
        float cs = 0.0f;
#pragma unroll
        for (int s = 0; s < NSHARD; s++) cs += csfin[s * 256 + tid];
        ev_lds[tid] = NUKS * __builtin_amdgcn_rcpf(cs);
    }
    __syncthreads();
    float4 ev = *(const float4*)&ev_lds[lane * 4];
    const int row0 = blockIdx.x * 64 + wave * 16;
    float acc = 0.0f;
    for (int r = 0; r < 16; r++) {
        const int row = row0 + r;
        float ai = aexp[row];
        float4 co = *(const float4*)&coord[(size_t)row * 256 + lane * 4];
        float a0 = fabsf(co.x), a1 = fabsf(co.y), a2 = fabsf(co.z), a3 = fabsf(co.w);
        float mx = wave_max(fmaxf(fmaxf(a0, a1), fmaxf(a2, a3)));
        float e0 = __expf(a0 - mx), e1 = __expf(a1 - mx);
        float e2 = __expf(a2 - mx), e3 = __expf(a3 - mx);
        float Z = wave_sum(e0 + e1 + e2 + e3);
        union { uint2 u; __half2 h[2]; } ku;
        ku.u = *(const uint2*)&kappa[(size_t)row * 256 + lane * 4];
        float2 k01 = __half22float2(ku.h[0]), k23 = __half22float2(ku.h[1]);
        float c0 = -0.1f * __logf(k01.x * INV_KSCALE - 1e-8f);
        float c1 = -0.1f * __logf(k01.y * INV_KSCALE - 1e-8f);
        float c2 = -0.1f * __logf(k23.x * INV_KSCALE - 1e-8f);
        float c3 = -0.1f * __logf(k23.y * INV_KSCALE - 1e-8f);
        float s = k01.x * ev.x * c0 * e0 + k01.y * ev.y * c1 * e1 +
                  k23.x * ev.z * c2 * e2 + k23.y * ev.w * c3 * e3;
        acc = fmaf(s, ai * INV_KSCALE * __builtin_amdgcn_rcpf(Z), acc);
    }
    acc = wave_sum(acc);
    if (lane == 0) wpart[wave] = acc;
    __syncthreads();
    if (tid == 0) atomicAdd(out, wpart[0] + wpart[1] + wpart[2] + wpart[3]);
}

extern "C" void kernel_launch(void* const* d_in, const int* in_sizes, int n_in,
                              void* d_out, int out_size, void* d_ws, size_t ws_size,
                              hipStream_t stream) {
    const float* x = (const float*)d_in[0];
    const float* proto = (const float*)d_in[1];
    const float* coord = (const float*)d_in[2];
    float* out = (float*)d_out;
    char* ws = (char*)d_ws;
    // workspace layout (~34.2 MB)
    __half* kappa = (__half*)(ws);                          // 32 MB
    float* yn = (float*)(ws + 33554432);                    // 128 KB
    float* rn = (float*)(ws + 33554432 + 131072);           // 256 KB
    float* aexp = (float*)(ws + 33554432 + 131072 + 262144);           // 256 KB
    float* csbuf = (float*)(ws + 33554432 + 131072 + 262144 + 262144); // 24 KB

    hipLaunchKernelGGL(proto_norm_init, dim3(257), dim3(64), 0, stream, proto, yn, csbuf, out);
    hipLaunchKernelGGL(row_norm, dim3(1024), dim3(256), 0, stream, x, rn);
    hipLaunchKernelGGL(gemm_kc, dim3(1024, 4), dim3(256), 0, stream, x, yn, rn, kappa);
    for (int t = 0; t < N_ITER; t++) {
        hipLaunchKernelGGL(sinkhorn_step, dim3(1024), dim3(256), 0, stream,
                           kappa, csbuf, aexp, t);
    }
    const float* csfin = csbuf + ((N_ITER - 1) % 3) * BUFSTRIDE;  // parity of t=49
    hipLaunchKernelGGL(finalize, dim3(1024), dim3(256), 0, stream, kappa, coord, aexp, csfin, out);
}